// Round 5
// baseline (120.252 us; speedup 1.0000x reference)
//
#include <hip/hip_runtime.h>

// Problem constants
constexpr int N = 8192;
constexpr int C = 2048;
constexpr int ND = N + 4;                        // 8196
constexpr unsigned ADJ_CHUNKS = ND / 4;          // 2049 float4 per adj row
constexpr unsigned TOTAL4 = (unsigned)ND * ADJ_CHUNKS;   // 16,793,604
constexpr size_t XNEW_ELEMS = (size_t)ND * C;    // 16785408
constexpr int ATT_BLOCKS = 512;                  // 16 rows each
constexpr int ADJ_BLOCKS = 2048;                 // grid-stride, ~32 iters

#define C_DIAG 0.5f
#define C_LINK 0.015609764f                      /* 1/sqrt(2*2052) */
#define C_BLK  (1.0f / 2052.0f)

// True vector type: __builtin_nontemporal_* accepts vectors of float,
// but NOT HIP's float4 wrapper class (R4 compile error).
typedef float f32x4 __attribute__((ext_vector_type(4)));

// ---------------------------------------------------------------------------
// adj streaming body: one nontemporal f32x4 store per 16B. Values built with
// per-component ternaries -> v_cndmask, v never touches scratch (rule #20:
// runtime-indexed float4 component writes spill to scratch -- the R3 bug).
__device__ __forceinline__ void adj_body(float* __restrict__ adj,
                                         unsigned first, unsigned stride) {
    f32x4* __restrict__ out = reinterpret_cast<f32x4*>(adj);
    for (unsigned i4 = first; i4 < TOTAL4; i4 += stride) {
        const unsigned row   = i4 / ADJ_CHUNKS;          // magic-mul div
        const unsigned chunk = i4 - row * ADJ_CHUNKS;
        f32x4 v;
        if (row < (unsigned)N) {
            const bool dg = (chunk == (row >> 2));       // diagonal chunk
            const bool lk = (chunk == 2048u);            // row -> center chunk
            const unsigned r3 = row & 3u, sg = row >> 11;
            v.x = (dg && r3 == 0u) ? C_DIAG : ((lk && sg == 0u) ? C_LINK : 0.0f);
            v.y = (dg && r3 == 1u) ? C_DIAG : ((lk && sg == 1u) ? C_LINK : 0.0f);
            v.z = (dg && r3 == 2u) ? C_DIAG : ((lk && sg == 2u) ? C_LINK : 0.0f);
            v.w = (dg && r3 == 3u) ? C_DIAG : ((lk && sg == 3u) ? C_LINK : 0.0f);
        } else {
            const unsigned a = row - N;                  // center row 0..3
            const float f = (chunk == 2048u) ? C_BLK
                          : (((chunk >> 9) == a) ? C_LINK : 0.0f);
            v.x = f; v.y = f; v.z = f; v.w = f;
        }
        __builtin_nontemporal_store(v, &out[i4]);
    }
}

// ---------------------------------------------------------------------------
// Fused kernel: blocks [0, ATT_BLOCKS) do the attention pass (16 rows each,
// per-wave partials -> ws, no LDS, no syncthreads); remaining blocks stream
// the adj pattern. Both are HBM-bound; co-residency keeps BW saturated.
__global__ __launch_bounds__(256) void k_fused(const float* __restrict__ x,
                                               const float* __restrict__ attw,
                                               const float* __restrict__ attb,
                                               float* __restrict__ xnew,
                                               float* __restrict__ adj,
                                               float* __restrict__ part,
                                               float* __restrict__ wpart) {
    const int tid = threadIdx.x;
    if (blockIdx.x < ATT_BLOCKS) {
        const int wave = tid >> 6;
        const int lane = tid & 63;
        const int row0 = blockIdx.x * 16;
        const float bias = attb[0];

        f32x4 wv[8];
#pragma unroll
        for (int q = 0; q < 8; ++q)
            wv[q] = reinterpret_cast<const f32x4*>(attw)[lane + 64 * q];

        float acc[32];
#pragma unroll
        for (int k = 0; k < 32; ++k) acc[k] = 0.0f;
        float wacc = 0.0f;

        for (int r = 0; r < 4; ++r) {
            const int row = row0 + wave * 4 + r;
            const f32x4* xrow = reinterpret_cast<const f32x4*>(x + (size_t)row * C);
            f32x4* orow = reinterpret_cast<f32x4*>(xnew + (size_t)row * C);

            f32x4 xv[8];
            float dot = 0.0f;
#pragma unroll
            for (int q = 0; q < 8; ++q) {
                xv[q] = __builtin_nontemporal_load(&xrow[lane + 64 * q]);
                dot += xv[q].x * wv[q].x + xv[q].y * wv[q].y +
                       xv[q].z * wv[q].z + xv[q].w * wv[q].w;
            }
#pragma unroll
            for (int off = 32; off > 0; off >>= 1) dot += __shfl_xor(dot, off, 64);
            const float wrow = dot + bias;
            wacc += wrow;
#pragma unroll
            for (int q = 0; q < 8; ++q) {
                acc[4 * q + 0] += wrow * xv[q].x;
                acc[4 * q + 1] += wrow * xv[q].y;
                acc[4 * q + 2] += wrow * xv[q].z;
                acc[4 * q + 3] += wrow * xv[q].w;
                __builtin_nontemporal_store(xv[q], &orow[lane + 64 * q]);
            }
        }

        // per-wave partial row (cached stores: k_centers re-reads these)
        const int gw = blockIdx.x * 4 + wave;            // 0..2047
        f32x4* prow = reinterpret_cast<f32x4*>(part + (size_t)gw * C);
#pragma unroll
        for (int q = 0; q < 8; ++q) {
            f32x4 s;
            s.x = acc[4 * q];     s.y = acc[4 * q + 1];
            s.z = acc[4 * q + 2]; s.w = acc[4 * q + 3];
            prow[lane + 64 * q] = s;
        }
        if (lane == 0) wpart[gw] = wacc;                 // wacc is wave-uniform
    } else {
        adj_body(adj, (blockIdx.x - ATT_BLOCKS) * 256u + (unsigned)tid,
                 ADJ_BLOCKS * 256u);
    }
}

// ---------------------------------------------------------------------------
// centers[seg][c] = sum_k part[seg*512+k][c] / sum_k wpart[seg*512+k]
__global__ __launch_bounds__(256) void k_centers(const float* __restrict__ part,
                                                 const float* __restrict__ wpart,
                                                 float* __restrict__ xnew) {
    const int idx = blockIdx.x * 256 + threadIdx.x;      // 0..8191
    const int seg = idx >> 11;
    const int c   = idx & 2047;
    float wsum = 0.0f;
#pragma unroll 8
    for (int k = 0; k < 512; ++k) wsum += wpart[seg * 512 + k];
    float s = 0.0f;
#pragma unroll 8
    for (int k = 0; k < 512; ++k) s += part[(size_t)(seg * 512 + k) * C + c];
    xnew[(size_t)(N + seg) * C + c] = s / wsum;
}

// ---------------------------------------------------------------------------
// Fallback path (ws too small): atomic accumulation, standalone adj kernel.
__global__ __launch_bounds__(256) void k_adj_only(float* __restrict__ adj) {
    adj_body(adj, blockIdx.x * 256u + (unsigned)threadIdx.x, ADJ_BLOCKS * 256u);
}
__global__ __launch_bounds__(256) void k_zero(float* __restrict__ xnew,
                                              float* __restrict__ wseg) {
    int idx = blockIdx.x * 256 + threadIdx.x;
    if (idx < 4 * C) xnew[(size_t)N * C + idx] = 0.0f;
    if (idx < 4) wseg[idx] = 0.0f;
}
__global__ __launch_bounds__(256) void k_att_atomic(const float* __restrict__ x,
                                                    const float* __restrict__ attw,
                                                    const float* __restrict__ attb,
                                                    float* __restrict__ xnew,
                                                    float* __restrict__ wseg) {
    __shared__ float lnum[4][C];
    __shared__ float lw[4];
    const int tid = threadIdx.x, wave = tid >> 6, lane = tid & 63;
    const int row0 = blockIdx.x * 16, seg = blockIdx.x >> 7;
    const float bias = attb[0];
    f32x4 wv[8];
#pragma unroll
    for (int q = 0; q < 8; ++q)
        wv[q] = reinterpret_cast<const f32x4*>(attw)[lane + 64 * q];
    float acc[32];
#pragma unroll
    for (int k = 0; k < 32; ++k) acc[k] = 0.0f;
    float wacc = 0.0f;
    for (int r = 0; r < 4; ++r) {
        const int row = row0 + wave * 4 + r;
        const f32x4* xrow = reinterpret_cast<const f32x4*>(x + (size_t)row * C);
        f32x4* orow = reinterpret_cast<f32x4*>(xnew + (size_t)row * C);
        f32x4 xv[8];
        float dot = 0.0f;
#pragma unroll
        for (int q = 0; q < 8; ++q) {
            xv[q] = xrow[lane + 64 * q];
            dot += xv[q].x * wv[q].x + xv[q].y * wv[q].y +
                   xv[q].z * wv[q].z + xv[q].w * wv[q].w;
        }
#pragma unroll
        for (int off = 32; off > 0; off >>= 1) dot += __shfl_xor(dot, off, 64);
        const float wrow = dot + bias;
        wacc += wrow;
#pragma unroll
        for (int q = 0; q < 8; ++q) {
            acc[4 * q + 0] += wrow * xv[q].x;
            acc[4 * q + 1] += wrow * xv[q].y;
            acc[4 * q + 2] += wrow * xv[q].z;
            acc[4 * q + 3] += wrow * xv[q].w;
            orow[lane + 64 * q] = xv[q];
        }
    }
#pragma unroll
    for (int q = 0; q < 8; ++q) {
        f32x4 s;
        s.x = acc[4 * q];     s.y = acc[4 * q + 1];
        s.z = acc[4 * q + 2]; s.w = acc[4 * q + 3];
        reinterpret_cast<f32x4*>(&lnum[wave][0])[lane + 64 * q] = s;
    }
    if (lane == 0) lw[wave] = wacc;
    __syncthreads();
    for (int c = tid; c < C; c += 256) {
        float s = lnum[0][c] + lnum[1][c] + lnum[2][c] + lnum[3][c];
        atomicAdd(&xnew[(size_t)(N + seg) * C + c], s);
    }
    if (tid == 0) atomicAdd(&wseg[seg], lw[0] + lw[1] + lw[2] + lw[3]);
}
__global__ __launch_bounds__(256) void k_div(float* __restrict__ xnew,
                                             const float* __restrict__ wseg) {
    int idx = blockIdx.x * 256 + threadIdx.x;
    if (idx < 4 * C) xnew[(size_t)N * C + idx] /= wseg[idx >> 11];
}

// ---------------------------------------------------------------------------
extern "C" void kernel_launch(void* const* d_in, const int* in_sizes, int n_in,
                              void* d_out, int out_size, void* d_ws, size_t ws_size,
                              hipStream_t stream) {
    const float* x    = (const float*)d_in[0];
    const float* attw = (const float*)d_in[1];
    const float* attb = (const float*)d_in[2];
    float* xnew = (float*)d_out;                   // [8196, 2048]
    float* adj  = (float*)d_out + XNEW_ELEMS;      // [8196, 8196]

    const size_t ws_need = (2048 + (size_t)2048 * C) * sizeof(float);  // ~16.8 MB
    if (ws_size >= ws_need) {
        float* wpart = (float*)d_ws;               // [2048]
        float* part  = (float*)d_ws + 2048;        // [2048][C]
        k_fused<<<ATT_BLOCKS + ADJ_BLOCKS, 256, 0, stream>>>(
            x, attw, attb, xnew, adj, part, wpart);
        k_centers<<<32, 256, 0, stream>>>(part, wpart, xnew);
    } else {                                        // atomic fallback
        float* wseg = (float*)d_ws;                // [4]
        k_zero<<<32, 256, 0, stream>>>(xnew, wseg);
        k_att_atomic<<<N / 16, 256, 0, stream>>>(x, attw, attb, xnew, wseg);
        k_div<<<32, 256, 0, stream>>>(xnew, wseg);
        k_adj_only<<<ADJ_BLOCKS, 256, 0, stream>>>(adj);
    }
}